// Round 4
// baseline (1004.923 us; speedup 1.0000x reference)
//
#include <hip/hip_runtime.h>
#include <math.h>

#define TT   512
#define BB   512
#define DIN  64
#define DLAT 128
#define KKK  192                 // DLAT + DIN

typedef _Float16 half8 __attribute__((ext_vector_type(8)));
typedef float    f32x4 __attribute__((ext_vector_type(4)));

#define MFMA16(A, B, C) __builtin_amdgcn_mfma_f32_16x16x32_f16((A), (B), (C), 0, 0, 0)

// LDS-only barrier: no vmcnt(0) drain (out-stores / x-loads stay in flight).
// Single memory-clobbered asm so no LDS op is scheduled across it.
#define BAR() asm volatile("s_waitcnt lgkmcnt(0)\n\ts_barrier" ::: "memory")

__device__ __forceinline__ float fsigmoid(float x) {
    float e = __builtin_amdgcn_exp2f(-1.44269504f * x);
    return __builtin_amdgcn_rcpf(1.f + e);
}
__device__ __forceinline__ float ftanh(float x) {
    float e = __builtin_amdgcn_exp2f(2.88539008f * x);
    return 1.f - 2.f * __builtin_amdgcn_rcpf(1.f + e);
}
__device__ __forceinline__ half8 cvt8(float4 a, float4 b) {
    return (half8){(_Float16)a.x, (_Float16)a.y, (_Float16)a.z, (_Float16)a.w,
                   (_Float16)b.x, (_Float16)b.y, (_Float16)b.z, (_Float16)b.w};
}

// Persistent GRU: 32 blocks x 256 threads (4 waves). Block owns 16 batch rows.
// Wave w owns output cols [32w,32w+32). Weights register-resident as MFMA
// B-frags (f16). h register-resident (C-layout slots reused across steps).
// LDS: only h (16x128) and h*r (16x128) f16 A-operand tiles, row-padded.
// x[t] A-frags are gather-loaded straight to registers, 1 step ahead.
__global__ __launch_bounds__(256, 1) void gru_mfma(
    const float* __restrict__ seqs, const float* __restrict__ h0,
    const float* __restrict__ bz, const float* __restrict__ br,
    const float* __restrict__ bi,
    const float* __restrict__ Wz, const float* __restrict__ Wr,
    const float* __restrict__ Wi, float* __restrict__ out)
{
    __shared__ __align__(16) _Float16 hA [16][136];
    __shared__ __align__(16) _Float16 hrA[16][136];

    const int tid = threadIdx.x;
    const int w   = tid >> 6;          // wave 0..3
    const int l   = tid & 63;
    const int q   = l >> 4;            // frag k-group
    const int ln  = l & 15;            // frag row/col index
    const int b0  = (int)blockIdx.x * 16;

    // ---- weight fragments -> registers (one-time) ----
    half8 wz[2][6], wr[2][6], wi[2][6];
    #pragma unroll
    for (int s = 0; s < 2; ++s) {
        const int n = 32 * w + 16 * s + ln;
        #pragma unroll
        for (int kt = 0; kt < 6; ++kt) {
            const int k0 = kt * 32 + q * 8;
            wz[s][kt] = cvt8(*(const float4*)&Wz[n * KKK + k0],
                             *(const float4*)&Wz[n * KKK + k0 + 4]);
            wr[s][kt] = cvt8(*(const float4*)&Wr[n * KKK + k0],
                             *(const float4*)&Wr[n * KKK + k0 + 4]);
            wi[s][kt] = cvt8(*(const float4*)&Wi[n * KKK + k0],
                             *(const float4*)&Wi[n * KKK + k0 + 4]);
        }
    }
    float bzv[2], brv[2], biv[2];
    #pragma unroll
    for (int s = 0; s < 2; ++s) {
        const int n = 32 * w + 16 * s + ln;
        bzv[s] = bz[n]; brv[s] = br[n]; biv[s] = bi[n];
    }

    // ---- h state in registers (C-layout slots) + hA + out[0] ----
    float h[2][4];
    #pragma unroll
    for (int s = 0; s < 2; ++s)
        #pragma unroll
        for (int i = 0; i < 4; ++i)
            h[s][i] = h0[(size_t)(b0 + 4 * q + i) * DLAT + 32 * w + 16 * s + ln];

    for (int idx = tid; idx < 16 * DLAT; idx += 256) {
        const int m = idx >> 7, c = idx & 127;
        const float v = h0[(size_t)(b0 + m) * DLAT + c];
        out[(size_t)(b0 + m) * DLAT + c] = v;
        hA[m][c] = (_Float16)v;
    }

    // ---- x[0] A-frags direct to registers ----
    const float* xb0 = seqs + ((size_t)0 * BB + b0 + ln) * DIN + q * 8;
    half8 xf0 = cvt8(*(const float4*)xb0,        *(const float4*)(xb0 + 4));
    half8 xf1 = cvt8(*(const float4*)(xb0 + 32), *(const float4*)(xb0 + 36));

    __syncthreads();

    // per-thread out pointer: first store goes to out[t=1]
    float* optr = out + (size_t)BB * DLAT
                      + (size_t)(b0 + 4 * q) * DLAT + 32 * w + ln;

    for (int t = 0; t < TT; ++t) {
        // prefetch x[t+1] A-frags (consumed next step; latency fully hidden)
        float4 nx0, nx1, nx2, nx3;
        const bool havext = (t + 1 < TT);
        if (havext) {
            const float* nb = seqs + ((size_t)(t + 1) * BB + b0 + ln) * DIN + q * 8;
            nx0 = *(const float4*)nb;        nx1 = *(const float4*)(nb + 4);
            nx2 = *(const float4*)(nb + 32); nx3 = *(const float4*)(nb + 36);
        }

        // ---- phase 1: z, r fully; cand's x-part (r-independent) ----
        half8 a0 = *(const half8*)&hA[ln][ 0 + q * 8];
        half8 a1 = *(const half8*)&hA[ln][32 + q * 8];
        half8 a2 = *(const half8*)&hA[ln][64 + q * 8];
        half8 a3 = *(const half8*)&hA[ln][96 + q * 8];

        f32x4 az[2], ar[2], ai[2];
        #pragma unroll
        for (int s = 0; s < 2; ++s) {
            az[s] = (f32x4){bzv[s], bzv[s], bzv[s], bzv[s]};
            ar[s] = (f32x4){brv[s], brv[s], brv[s], brv[s]};
            ai[s] = (f32x4){biv[s], biv[s], biv[s], biv[s]};
        }
        #pragma unroll
        for (int s = 0; s < 2; ++s) {
            az[s] = MFMA16(a0, wz[s][0], az[s]);
            az[s] = MFMA16(a1, wz[s][1], az[s]);
            az[s] = MFMA16(a2, wz[s][2], az[s]);
            az[s] = MFMA16(a3, wz[s][3], az[s]);
            az[s] = MFMA16(xf0, wz[s][4], az[s]);
            az[s] = MFMA16(xf1, wz[s][5], az[s]);
            ar[s] = MFMA16(a0, wr[s][0], ar[s]);
            ar[s] = MFMA16(a1, wr[s][1], ar[s]);
            ar[s] = MFMA16(a2, wr[s][2], ar[s]);
            ar[s] = MFMA16(a3, wr[s][3], ar[s]);
            ar[s] = MFMA16(xf0, wr[s][4], ar[s]);
            ar[s] = MFMA16(xf1, wr[s][5], ar[s]);
            ai[s] = MFMA16(xf0, wi[s][4], ai[s]);
            ai[s] = MFMA16(xf1, wi[s][5], ai[s]);
        }

        float zz[2][4];
        #pragma unroll
        for (int s = 0; s < 2; ++s)
            #pragma unroll
            for (int i = 0; i < 4; ++i) {
                zz[s][i]      = fsigmoid(az[s][i]);
                const float r = fsigmoid(ar[s][i]);
                hrA[4 * q + i][32 * w + 16 * s + ln] = (_Float16)(h[s][i] * r);
            }

        BAR();   // hr visible (LDS only; out-stores/x-loads stay in flight)

        // ---- phase 2: cand h*r part ----
        half8 c0 = *(const half8*)&hrA[ln][ 0 + q * 8];
        half8 c1 = *(const half8*)&hrA[ln][32 + q * 8];
        half8 c2 = *(const half8*)&hrA[ln][64 + q * 8];
        half8 c3 = *(const half8*)&hrA[ln][96 + q * 8];
        #pragma unroll
        for (int s = 0; s < 2; ++s) {
            ai[s] = MFMA16(c0, wi[s][0], ai[s]);
            ai[s] = MFMA16(c1, wi[s][1], ai[s]);
            ai[s] = MFMA16(c2, wi[s][2], ai[s]);
            ai[s] = MFMA16(c3, wi[s][3], ai[s]);
        }

        #pragma unroll
        for (int s = 0; s < 2; ++s)
            #pragma unroll
            for (int i = 0; i < 4; ++i) {
                const float cand = ftanh(ai[s][i]);
                const float hn   = h[s][i] + zz[s][i] * (cand - h[s][i]);
                h[s][i] = hn;
                hA[4 * q + i][32 * w + 16 * s + ln] = (_Float16)hn;
                optr[i * DLAT + 16 * s] = hn;
            }
        optr += (size_t)BB * DLAT;

        if (havext) { xf0 = cvt8(nx0, nx1); xf1 = cvt8(nx2, nx3); }

        BAR();   // new h visible for next step's fragments
    }
}

extern "C" void kernel_launch(void* const* d_in, const int* in_sizes, int n_in,
                              void* d_out, int out_size, void* d_ws, size_t ws_size,
                              hipStream_t stream) {
    const float* seqs = (const float*)d_in[0];
    const float* h0   = (const float*)d_in[1];
    const float* Wz   = (const float*)d_in[2];
    const float* bz   = (const float*)d_in[3];
    const float* Wr   = (const float*)d_in[4];
    const float* br   = (const float*)d_in[5];
    const float* Wi   = (const float*)d_in[6];
    const float* bi   = (const float*)d_in[7];
    float* out = (float*)d_out;

    gru_mfma<<<BB / 16, 256, 0, stream>>>(seqs, h0, bz, br, bi, Wz, Wr, Wi, out);
}